// Round 11
// baseline (1472.185 us; speedup 1.0000x reference)
//
#include <hip/hip_runtime.h>

#define NROWS 8192
#define TPB   1024
#define NBLK  256
#define NCELL 99            // 3 halo rows x 33 halo cols
#define SCALE 0.1714985851425088f   // 1/sqrt(34)
#define INV64 0.015625f

// workspace layout (float offsets)
#define OFF_W1   0          // 1024
#define OFF_W2   1024       // 1024
#define OFF_WIN  2048       // 3468
#define OFF_WFC2 5516       // 1024
#define OFF_M    6540       // 1088
#define OFF_B12  7628       // 32
#define OFF_BIN  7660       // 102
#define OFF_B2   7762       // 32
#define OFF_BFC2 7794       // 32
#define OFF_LNG  7826       // 32
#define OFF_LNB  7858       // 32
#define OFF_QKV0 8192
#define QKVN     (NROWS*102)         // feature-major qkv buffer
#define HNN      (NROWS*32)          // row-major hnew buffer
#define OFF_HN0  (OFF_QKV0 + 2*QKVN)

__global__ __launch_bounds__(256) void setup_kernel(
    const float* __restrict__ W_x2h, const float* __restrict__ b_x2h,
    const float* __restrict__ W_h2h, const float* __restrict__ b_h2h,
    const float* __restrict__ W_fc2, const float* __restrict__ b_fc2,
    const float* __restrict__ ln_g,  const float* __restrict__ ln_b,
    const float* __restrict__ W_fcsa,const float* __restrict__ b_fcsa,
    const float* __restrict__ W_in,  const float* __restrict__ b_in,
    const float* __restrict__ W_out, const float* __restrict__ b_out,
    float* __restrict__ ws)
{
  int t = blockIdx.x*blockDim.x + threadIdx.x;
  int stride = gridDim.x*blockDim.x;
  for (int i=t;i<1024;i+=stride) ws[OFF_W1+i]   = W_x2h[i];
  for (int i=t;i<1024;i+=stride) ws[OFF_W2+i]   = W_h2h[i];
  for (int i=t;i<3468;i+=stride) ws[OFF_WIN+i]  = W_in[i];
  for (int i=t;i<1024;i+=stride) ws[OFF_WFC2+i] = W_fc2[i];
  for (int i=t;i<32;i+=stride)   ws[OFF_B12+i]  = b_x2h[i] + b_h2h[i];
  for (int i=t;i<102;i+=stride)  ws[OFF_BIN+i]  = b_in[i];
  for (int i=t;i<32;i+=stride)   ws[OFF_BFC2+i] = b_fc2[i];
  for (int i=t;i<32;i+=stride)   ws[OFF_LNG+i]  = ln_g[i];
  for (int i=t;i<32;i+=stride)   ws[OFF_LNB+i]  = ln_b[i];
  // M = W_fcsa (32x34) @ W_out (34x34)
  for (int idx=t; idx<1088; idx+=stride) {
    int j = idx/34, f = idx - j*34;
    float acc = 0.f;
    for (int e=0;e<34;++e)
      acc += W_fcsa[j*34+e] * W_out[e*34+f];
    ws[OFF_M+idx] = acc;
  }
  for (int j=t;j<32;j+=stride){
    float acc = b_fcsa[j];
    for (int e=0;e<34;++e) acc += W_fcsa[j*34+e] * b_out[e];
    ws[OFF_B2+j] = acc;
  }
}

// Fused-2 step kernel: one launch = steps (2l, 2l+1) via halo redundancy.
// Block = (batch, grid-row, col-half): own cells 1x32; halo 3 rows x 33 cols.
//  P1: attention+finish of step 2l-1 for ALL 99 halo cells (global qkv/hnew,
//      written by launch l-1) -> h', pred; own slice -> out[2l-1].
//  P2: rnn+qkv of step 2l for 99 halo cells; qkv^{2l} stays in LDS.
//  P3: attention of step 2l for own 32 cells, PURE LDS -> h', pred, out[2l].
//  P4: rnn+qkv of step 2l+1 for own cells -> global (qkvW, hnW).
// Redundant compute (~2x) buys out one full launch + one qkv global
// round-trip per step pair. Coherence = launch boundaries only.
// All per-cell-vector LDS arrays are [feat][cell] (transposed) with odd
// strides so every phase's access pattern is bank-conflict-free.
__global__ __launch_bounds__(TPB) void fused2_kernel(
    const float* __restrict__ ws,
    const float* __restrict__ qkvR,   // qkv^{2l-1} (read)
    float* __restrict__ qkvW,         // qkv^{2l+1} (write)
    const float* __restrict__ hnR,    // hnew^{2l-1} row-major (read)
    float* __restrict__ hnW,          // hnew^{2l+1} row-major (write)
    const float* __restrict__ x,
    float* __restrict__ out,
    int l)
{
  __shared__ float sW1[32][33], sW2[32][33], sWfc2[32][33];
  __shared__ float sM[32][35];
  __shared__ float sWin[102][35];
  __shared__ float sB12[32], sBin[102], sB2[32], sBfc2[32], sLng[32], sLnb[32];
  __shared__ float sHp  [32][NCELL];   // h-state, transposed [feat][cell]
  __shared__ float sPredT[32][NCELL];
  __shared__ float sHnT [32][NCELL];
  __shared__ float sGT  [32][NCELL];
  __shared__ float sS[NCELL][13];      // scores (9, stride 13 conflict-free)
  __shared__ float uOX[36][102];       // union: attn-o [34][cell] / x1 [32][cell]
  __shared__ float sX2[32][33];
  __shared__ float sQKV2[3][102][37];  // qkv^{2l}: [halo row][feat][halo col]

  const int tid = threadIdx.x;
  const int bid = blockIdx.x;
  const int b   = bid >> 7;            // batch
  const int gr  = (bid >> 1) & 63;     // grid-row
  const int ch  = bid & 1;             // col-half
  const int c0  = ch << 5;
  const int br  = (gr < 1) ? 1 : ((gr > 62) ? 62 : gr);
  const int R0  = br - 1;              // first halo row
  const int C0  = ch ? 31 : 0;         // first halo col
  const int rr_own = gr - R0;
  const int cc0 = c0 - C0;             // own-col offset in halo (0 or 1)
  const int ownbase = (b<<12) + (gr<<6) + c0;
  const int sPrev = 2*l - 1, sEven = 2*l, sOdd = 2*l + 1;
  const bool hasP1 = (l >= 1);
  const bool hasP4 = (sOdd <= 58);

  // ---- phase A: stage weights/biases + inputs ----
  {
    int j = tid >> 5, i = tid & 31;
    sW1[j][i]   = ws[OFF_W1  + tid];
    sW2[j][i]   = ws[OFF_W2  + tid];
    sWfc2[j][i] = ws[OFF_WFC2+ tid];
    for (int idx = tid; idx < 1088; idx += TPB){ int jj=idx/34, e=idx-jj*34; sM[jj][e]=ws[OFF_M+idx]; }
    for (int idx = tid; idx < 3468; idx += TPB){ int e=idx/34, f=idx-e*34; sWin[e][f]=ws[OFF_WIN+idx]; }
    if (tid < 102)                sBin [tid]     = ws[OFF_BIN + tid];
    else if (tid>=128 && tid<160) sB12 [tid-128] = ws[OFF_B12 + tid-128];
    else if (tid>=160 && tid<192) sB2  [tid-160] = ws[OFF_B2  + tid-160];
    else if (tid>=192 && tid<224) sBfc2[tid-192] = ws[OFF_BFC2+ tid-192];
    else if (tid>=224 && tid<256) sLng [tid-224] = ws[OFF_LNG + tid-224];
    else if (tid>=256 && tid<288) sLnb [tid-256] = ws[OFF_LNB + tid-256];
  }
  if (l == 0) {
    for (int tt = tid; tt < 3168; tt += TPB) {
      int cell = tt >> 5, j = tt & 31;
      sHp[j][cell] = 0.f;                               // h^{-1} = 0
      int rr = cell/33, cc = cell - rr*33;
      int ar = (b<<12) + ((R0+rr)<<6) + C0 + cc;
      uOX[j][cell] = x[(size_t)ar*32 + j];              // x_0
    }
  }
  if (hasP4 && sOdd < 10) {
    int cell = tid >> 5, j = tid & 31;
    sX2[cell][j] = x[((size_t)sOdd*NROWS + ownbase + cell)*32 + j];
  }
  __syncthreads();

  // ================= P1: attention+finish of step 2l-1 (99 halo cells) ====
  if (hasP1) {
    if (tid < 891) {                    // scores: (cell, m)
      int m = tid / 99, cell = tid - m*99;
      int rr = cell/33, cc = cell - rr*33;
      int g = R0+rr, c = C0+cc;
      int bg  = (g<1)?1:((g>62)?62:g);
      int bcc = (c<1)?1:((c>62)?62:c);
      int dr = m/3 - 1, dc = m - (m/3)*3 - 1;
      int qrow = (b<<12)+(bg<<6)+bcc;
      int krow = (b<<12)+((bg+dr)<<6)+(bcc+dc);
      float acc = 0.f;
      #pragma unroll
      for (int e=0;e<34;++e)
        acc += qkvR[(size_t)e*NROWS+qrow]*qkvR[(size_t)(34+e)*NROWS+krow];
      sS[cell][m] = acc*SCALE;
    }
    __syncthreads();
    if (tid < 990) {                    // softmax + o: 10 threads/cell
      int sub = tid / 99, cell = tid - sub*99;
      int rr = cell/33, cc = cell - rr*33;
      int g = R0+rr, c = C0+cc;
      int bg  = (g<1)?1:((g>62)?62:g);
      int bcc = (c<1)?1:((c>62)?62:c);
      float sc[9]; float mx = -1e30f;
      #pragma unroll
      for (int m=0;m<9;++m){ sc[m]=sS[cell][m]; mx=fmaxf(mx,sc[m]); }
      float sum=0.f;
      #pragma unroll
      for (int m=0;m<9;++m){ sc[m]=__expf(sc[m]-mx); sum+=sc[m]; }
      float inv = 1.f/sum;
      const int f0=sub, f1=sub+10, f2=sub+20, f3=sub+30;
      const bool h3 = (sub < 4);
      float o0=0.f,o1=0.f,o2=0.f,o3=0.f;
      #pragma unroll
      for (int m=0;m<9;++m){
        int dr = m/3 - 1, dc = m - (m/3)*3 - 1;
        int krow = (b<<12)+((bg+dr)<<6)+(bcc+dc);
        float wm = sc[m]*inv;
        o0 += wm*qkvR[(size_t)(68+f0)*NROWS+krow];
        o1 += wm*qkvR[(size_t)(68+f1)*NROWS+krow];
        o2 += wm*qkvR[(size_t)(68+f2)*NROWS+krow];
        if (h3) o3 += wm*qkvR[(size_t)(68+f3)*NROWS+krow];
      }
      uOX[f0][cell]=o0; uOX[f1][cell]=o1; uOX[f2][cell]=o2;
      if (h3) uOX[f3][cell]=o3;
    }
    __syncthreads();
    for (int tt = tid; tt < 3168; tt += TPB) {   // h' = hnew + o@M^T + b2
      int cell = tt>>5, j = tt&31;
      int rr = cell/33, cc = cell - rr*33;
      int ar = (b<<12)+((R0+rr)<<6)+C0+cc;
      float a = sB2[j] + hnR[(size_t)ar*32 + j];
      #pragma unroll
      for (int e=0;e<34;++e) a += uOX[e][cell]*sM[j][e];
      sHp[j][cell] = a;
    }
    __syncthreads();
    for (int tt = tid; tt < 3168; tt += TPB) {   // fc2 (+ x1 prefetch)
      int cell = tt>>5, j = tt&31;
      float g2 = sBfc2[j];
      #pragma unroll
      for (int i=0;i<32;++i) g2 += sHp[i][cell]*sWfc2[j][i];
      sGT[j][cell] = g2;
      if (sEven < 10) {                 // overwrite dead o-region with x_{2l}
        int rr = cell/33, cc = cell - rr*33;
        int ar = (b<<12)+((R0+rr)<<6)+C0+cc;
        uOX[j][cell] = x[((size_t)sEven*NROWS + ar)*32 + j];
      }
    }
    __syncthreads();
    for (int tt = tid; tt < 3168; tt += TPB) {   // layernorm -> pred^{2l-1}
      int cell = tt>>5, j = tt&31;
      float mu=0.f;
      #pragma unroll
      for (int i=0;i<32;++i) mu += sGT[i][cell];
      mu *= 0.03125f;
      float var=0.f;
      #pragma unroll
      for (int i=0;i<32;++i){ float d=sGT[i][cell]-mu; var += d*d; }
      var *= 0.03125f;
      float rs = rsqrtf(var + 1e-5f);
      sPredT[j][cell] = (sGT[j][cell]-mu)*rs*sLng[j] + sLnb[j];
    }
    __syncthreads();
  }

  // ================= P2: rnn + qkv of step 2l (99 halo cells) =============
  {
    if (hasP1) {                        // out[2l-1] (own cells), coalesced
      int cell = tid>>5, j = tid&31;
      int cellh = rr_own*33 + cc0 + cell;
      out[((size_t)sPrev*NROWS + ownbase + cell)*32 + j] = sPredT[j][cellh];
    }
    for (int tt = tid; tt < 3168; tt += TPB) {   // hnew^{2l}
      int cell = tt>>5, j = tt&31;
      float a = sB12[j];
      if (sEven < 10) {
        #pragma unroll
        for (int i=0;i<32;++i) a += uOX[i][cell]*sW1[j][i] + sHp[i][cell]*sW2[j][i];
      } else {
        #pragma unroll
        for (int i=0;i<32;++i) a += sPredT[i][cell]*sW1[j][i] + sHp[i][cell]*sW2[j][i];
      }
      sHnT[j][cell] = tanhf(a);
    }
    __syncthreads();
    for (int tt = tid; tt < 10098; tt += TPB) {  // qkv^{2l} -> LDS
      int e = tt / 99, cell = tt - e*99;
      int rr = cell/33, cc = cell - rr*33;
      float acc = sBin[e];
      #pragma unroll
      for (int f=0; f<32; ++f) acc += sHnT[f][cell]*sWin[e][f];
      acc += (R0+rr)*INV64*sWin[e][32] + (C0+cc)*INV64*sWin[e][33];
      sQKV2[rr][e][cc] = acc;
    }
    __syncthreads();
  }

  // ================= P3: attention of step 2l (own 32 cells, pure LDS) ====
  {
    if (tid < 288) {                    // scores
      int m = tid>>5, cell = tid&31;
      int c = c0 + cell;
      int bcc = (c<1)?1:((c>62)?62:c);
      int dr = m/3 - 1, dc = m - (m/3)*3 - 1;
      int colq = bcc - C0, colk = bcc + dc - C0, rrk = 1 + dr;
      float acc = 0.f;
      #pragma unroll
      for (int e=0;e<34;++e) acc += sQKV2[1][e][colq]*sQKV2[rrk][34+e][colk];
      sS[cell][m] = acc*SCALE;
    }
    __syncthreads();
    if (tid < 320) {                    // softmax + o
      int sub = tid>>5, cell = tid&31;
      int c = c0 + cell;
      int bcc = (c<1)?1:((c>62)?62:c);
      float sc[9]; float mx = -1e30f;
      #pragma unroll
      for (int m=0;m<9;++m){ sc[m]=sS[cell][m]; mx=fmaxf(mx,sc[m]); }
      float sum=0.f;
      #pragma unroll
      for (int m=0;m<9;++m){ sc[m]=__expf(sc[m]-mx); sum+=sc[m]; }
      float inv = 1.f/sum;
      const int f0=sub, f1=sub+10, f2=sub+20, f3=sub+30;
      const bool h3 = (sub < 4);
      float o0=0.f,o1=0.f,o2=0.f,o3=0.f;
      #pragma unroll
      for (int m=0;m<9;++m){
        int dr = m/3 - 1, dc = m - (m/3)*3 - 1;
        int colk = bcc + dc - C0, rrk = 1 + dr;
        float wm = sc[m]*inv;
        o0 += wm*sQKV2[rrk][68+f0][colk];
        o1 += wm*sQKV2[rrk][68+f1][colk];
        o2 += wm*sQKV2[rrk][68+f2][colk];
        if (h3) o3 += wm*sQKV2[rrk][68+f3][colk];
      }
      uOX[f0][cell]=o0; uOX[f1][cell]=o1; uOX[f2][cell]=o2;
      if (h3) uOX[f3][cell]=o3;
    }
    __syncthreads();
    {                                   // h'^{2l} (own)
      int cell = tid>>5, j = tid&31;
      int cellh = rr_own*33 + cc0 + cell;
      float a = sB2[j] + sHnT[j][cellh];
      #pragma unroll
      for (int e=0;e<34;++e) a += uOX[e][cell]*sM[j][e];
      sHp[j][cellh] = a;
    }
    __syncthreads();
    {                                   // fc2 (own)
      int cell = tid>>5, j = tid&31;
      int cellh = rr_own*33 + cc0 + cell;
      float g2 = sBfc2[j];
      #pragma unroll
      for (int i=0;i<32;++i) g2 += sHp[i][cellh]*sWfc2[j][i];
      sGT[j][cellh] = g2;
    }
    __syncthreads();
    {                                   // layernorm -> pred^{2l} (own)
      int cell = tid>>5, j = tid&31;
      int cellh = rr_own*33 + cc0 + cell;
      float mu=0.f;
      #pragma unroll
      for (int i=0;i<32;++i) mu += sGT[i][cellh];
      mu *= 0.03125f;
      float var=0.f;
      #pragma unroll
      for (int i=0;i<32;++i){ float d=sGT[i][cellh]-mu; var += d*d; }
      var *= 0.03125f;
      float rs = rsqrtf(var + 1e-5f);
      sPredT[j][cellh] = (sGT[j][cellh]-mu)*rs*sLng[j] + sLnb[j];
    }
    __syncthreads();
  }

  // ================= P4: out[2l] + rnn/qkv of step 2l+1 (own) =============
  {
    int cell = tid>>5, j = tid&31;
    int cellh = rr_own*33 + cc0 + cell;
    out[((size_t)sEven*NROWS + ownbase + cell)*32 + j] = sPredT[j][cellh];
    if (hasP4) {
      float a = sB12[j];
      if (sOdd < 10) {
        #pragma unroll
        for (int i=0;i<32;++i) a += sX2[cell][i]*sW1[j][i] + sHp[i][cellh]*sW2[j][i];
      } else {
        #pragma unroll
        for (int i=0;i<32;++i) a += sPredT[i][cellh]*sW1[j][i] + sHp[i][cellh]*sW2[j][i];
      }
      float tv = tanhf(a);
      sHnT[j][cellh] = tv;
      hnW[((size_t)ownbase + cell)*32 + j] = tv;     // row-major, coalesced
    }
  }
  if (hasP4) {
    __syncthreads();
    for (int tt = tid; tt < 3264; tt += TPB) {       // qkv^{2l+1} -> global
      int e = tt>>5, cell = tt&31;
      int cellh = rr_own*33 + cc0 + cell;
      float acc = sBin[e];
      #pragma unroll
      for (int f=0;f<32;++f) acc += sHnT[f][cellh]*sWin[e][f];
      acc += gr*INV64*sWin[e][32] + (c0+cell)*INV64*sWin[e][33];
      qkvW[(size_t)e*NROWS + ownbase + cell] = acc;  // 128B coalesced per e
    }
  }
}

extern "C" void kernel_launch(void* const* d_in, const int* in_sizes, int n_in,
                              void* d_out, int out_size, void* d_ws, size_t ws_size,
                              hipStream_t stream) {
  const float* x     = (const float*)d_in[0];
  const float* W_x2h = (const float*)d_in[1];
  const float* b_x2h = (const float*)d_in[2];
  const float* W_h2h = (const float*)d_in[3];
  const float* b_h2h = (const float*)d_in[4];
  const float* W_fc2 = (const float*)d_in[5];
  const float* b_fc2 = (const float*)d_in[6];
  const float* ln_g  = (const float*)d_in[7];
  const float* ln_b  = (const float*)d_in[8];
  const float* W_fcsa= (const float*)d_in[9];
  const float* b_fcsa= (const float*)d_in[10];
  const float* W_in  = (const float*)d_in[11];
  const float* b_in  = (const float*)d_in[12];
  const float* W_out = (const float*)d_in[13];
  const float* b_out = (const float*)d_in[14];
  float* ws = (float*)d_ws;
  float* out = (float*)d_out;

  setup_kernel<<<8, 256, 0, stream>>>(W_x2h,b_x2h,W_h2h,b_h2h,W_fc2,b_fc2,ln_g,ln_b,
                                      W_fcsa,b_fcsa,W_in,b_in,W_out,b_out, ws);
  for (int l = 0; l < 30; ++l) {
    const float* qR = ws + OFF_QKV0 + (size_t)((l+1)&1)*QKVN;  // qkv^{2l-1}
    float*       qW = ws + OFF_QKV0 + (size_t)(l&1)*QKVN;      // qkv^{2l+1}
    const float* hR = ws + OFF_HN0  + (size_t)((l+1)&1)*HNN;   // hnew^{2l-1}
    float*       hW = ws + OFF_HN0  + (size_t)(l&1)*HNN;       // hnew^{2l+1}
    fused2_kernel<<<NBLK, TPB, 0, stream>>>(ws, qR, qW, hR, hW, x, out, l);
  }
}

// Round 13
// 1265.163 us; speedup vs baseline: 1.1636x; 1.1636x over previous
//
#include <hip/hip_runtime.h>

#define NROWS 8192
#define RPB   16       // rows per block
#define TPB   1024     // 16 waves; slot = tid>>4 (0..63), row = tid&15
#define NBLK  512      // 2 blocks/CU -> 8 waves/SIMD (latency hiding)

// workspace layout (float offsets)
#define OFF_W1   0          // 1024
#define OFF_W2   1024       // 1024
#define OFF_WIN  2048       // 102*34 = 3468
#define OFF_WFC2 5516       // 1024
#define OFF_M    6540       // 32*34 = 1088
#define OFF_B12  7628       // 32
#define OFF_BIN  7660       // 102
#define OFF_B2   7762       // 32
#define OFF_BFC2 7794       // 32
#define OFF_LNG  7826       // 32
#define OFF_LNB  7858       // 32
#define OFF_QKV0 8192
#define QKVN     (NROWS*102)          // feature-major: qkv[e][row]
#define OFF_QKV1 (OFF_QKV0 + QKVN)
#define OFF_HNEW (OFF_QKV1 + QKVN)   // feature-major: hnew[j][row], 32*NROWS

__global__ __launch_bounds__(256) void setup_kernel(
    const float* __restrict__ W_x2h, const float* __restrict__ b_x2h,
    const float* __restrict__ W_h2h, const float* __restrict__ b_h2h,
    const float* __restrict__ W_fc2, const float* __restrict__ b_fc2,
    const float* __restrict__ ln_g,  const float* __restrict__ ln_b,
    const float* __restrict__ W_fcsa,const float* __restrict__ b_fcsa,
    const float* __restrict__ W_in,  const float* __restrict__ b_in,
    const float* __restrict__ W_out, const float* __restrict__ b_out,
    float* __restrict__ ws)
{
  int t = blockIdx.x*blockDim.x + threadIdx.x;
  int stride = gridDim.x*blockDim.x;
  for (int i=t;i<1024;i+=stride) ws[OFF_W1+i]   = W_x2h[i];
  for (int i=t;i<1024;i+=stride) ws[OFF_W2+i]   = W_h2h[i];
  for (int i=t;i<3468;i+=stride) ws[OFF_WIN+i]  = W_in[i];
  for (int i=t;i<1024;i+=stride) ws[OFF_WFC2+i] = W_fc2[i];
  for (int i=t;i<32;i+=stride)   ws[OFF_B12+i]  = b_x2h[i] + b_h2h[i];
  for (int i=t;i<102;i+=stride)  ws[OFF_BIN+i]  = b_in[i];
  for (int i=t;i<32;i+=stride)   ws[OFF_BFC2+i] = b_fc2[i];
  for (int i=t;i<32;i+=stride)   ws[OFF_LNG+i]  = ln_g[i];
  for (int i=t;i<32;i+=stride)   ws[OFF_LNB+i]  = ln_b[i];
  // M = W_fcsa (32x34) @ W_out (34x34)
  for (int idx=t; idx<1088; idx+=stride) {
    int j = idx/34, f = idx - j*34;
    float acc = 0.f;
    for (int e=0;e<34;++e)
      acc += W_fcsa[j*34+e] * W_out[e*34+f];
    ws[OFF_M+idx] = acc;
  }
  for (int j=t;j<32;j+=stride){
    float acc = b_fcsa[j];
    for (int e=0;e<34;++e) acc += W_fcsa[j*34+e] * b_out[e];
    ws[OFF_B2+j] = acc;
  }
}

// Multi-launch step kernel (R10 structure, re-partitioned for 2 blocks/CU):
// 16 rows/block, 512 blocks, 1024 threads. slot = tid>>4 (0..63), row=tid&15.
// LDS ~47 KB and VGPR ~52 -> two blocks co-resident per CU (8 waves/SIMD):
// when one block stalls on a barrier or a global qkv read, the other block's
// waves issue — attacks the latency-chain bottleneck R10 exposed (2x CUs
// gave only +4.5% -> each launch is latency-bound, not throughput-bound).
// Weights staged in LDS (slot varies within wave, so no s_load path); LDS
// weight reads broadcast across the 16 row-lanes (free).
// [R12 note: identical logic resubmitted — R12 bench was an infra failure
//  ("container failed twice"), not a kernel verdict; no exotic features here.]
__global__ __launch_bounds__(TPB) void step_kernel(
    const float* __restrict__ ws,
    const float* __restrict__ qkvR,     // qkv of step stepB (read)
    float* __restrict__ qkvW,           // qkv of step stepA (write)
    float* __restrict__ hnewG,          // feature-major tanh-state
    const float* __restrict__ x,
    float* __restrict__ out,
    int stepB, int stepA)
{
  __shared__ float sW1[32][33], sW2[32][33], sWfc2[32][33];
  __shared__ float sM[32][36];
  __shared__ float sWin[102][36];
  __shared__ float sB12[32], sBin[102], sB2[32], sBfc2[32], sLng[32], sLnb[32];
  __shared__ float sS[RPB][13];      // 9 scores (odd stride: conflict-free)
  __shared__ float sO[RPB][35];      // attention output (34)
  __shared__ float sHp[RPB][33];     // h' (prestaged hnew + attention)
  __shared__ float sG[RPB][33];      // pre-LN fc2 output
  __shared__ float sPred[RPB][33];   // pred (next-step input)
  __shared__ float sHn[RPB][33];     // h_new (tanh output)
  __shared__ float sX[RPB][33];      // staged x chunk (steps 0..9)

  const int tid  = threadIdx.x;
  const int lr2  = tid & 15;         // row within block
  const int slot = tid >> 4;         // work slot 0..63
  const int base = blockIdx.x * RPB;
  const int r2   = base + lr2;
  const int b    = base >> 12;       // batch (uniform)
  const int p    = base & 4095;
  const int gr   = p >> 6;           // grid-row (uniform)
  const int gc0  = p & 63;           // 0/16/32/48 (uniform)
  const int c    = gc0 + lr2;        // global column (per-lane)
  const int br   = (gr < 1) ? 1 : ((gr > 62) ? 62 : gr);
  const int bc   = (c  < 1) ? 1 : ((c  > 62) ? 62 : c);

  // ---- phase A (no deps, fully concurrent): stage weights/biases + x,
  //      prestage hnew (slots 32..63), scores (slots 0..8) ----
  {
    sW1  [tid>>5][tid&31] = ws[OFF_W1  +tid];
    sW2  [tid>>5][tid&31] = ws[OFF_W2  +tid];
    sWfc2[tid>>5][tid&31] = ws[OFF_WFC2+tid];
    for (int idx=tid; idx<1088; idx+=TPB){ int j=idx/34, e=idx-j*34; sM[j][e]=ws[OFF_M+idx]; }
    for (int idx=tid; idx<3468; idx+=TPB){ int e=idx/34, f=idx-e*34; sWin[e][f]=ws[OFF_WIN+idx]; }
    if (tid < 102)                    sBin [tid]     = ws[OFF_BIN +tid];
    else if (tid>=128 && tid<160)     sB12 [tid-128] = ws[OFF_B12 +tid-128];
    else if (tid>=160 && tid<192)     sB2  [tid-160] = ws[OFF_B2  +tid-160];
    else if (tid>=192 && tid<224)     sBfc2[tid-192] = ws[OFF_BFC2+tid-192];
    else if (tid>=224 && tid<256)     sLng [tid-224] = ws[OFF_LNG +tid-224];
    else if (tid>=256 && tid<288)     sLnb [tid-256] = ws[OFF_LNB +tid-256];
  }
  if (stepA >= 0 && stepA < 10 && tid < 512) {
    size_t xbase = ((size_t)stepA*NROWS + base)*32;
    sX[tid>>5][tid&31] = x[xbase + tid];           // 512 floats, coalesced
  }
  if (stepB >= 0) {
    if (slot >= 32) {                               // prestage hnew -> sHp
      const int j = slot - 32;
      sHp[lr2][j] = hnewG[(size_t)j*NROWS + r2];
    } else if (slot < 9) {                          // scores, m = slot
      const int m  = slot;
      const int dr = m/3 - 1, dc = m - (m/3)*3 - 1;
      const int qrow = (b<<12) + (br<<6) + bc;
      const int nr_  = (b<<12) + ((br+dr)<<6) + (bc+dc);
      float acc = 0.f;
      #pragma unroll
      for (int e=0;e<34;++e)
        acc += qkvR[(size_t)e*NROWS + qrow] * qkvR[(size_t)(34+e)*NROWS + nr_];
      sS[lr2][m] = acc * 0.1714985851425088f;       // 1/sqrt(34)
    }
  } else {
    if (slot < 32) sHp[lr2][slot] = 0.f;            // step 0: h' = 0
  }
  __syncthreads();

  if (stepB >= 0) {
    // ---- softmax (redundant per slot) + o feature : slot -> e = slot<34 ----
    if (slot < 34) {
      float sc[9]; float mx = -1e30f;
      #pragma unroll
      for (int m=0;m<9;++m){ sc[m]=sS[lr2][m]; mx=fmaxf(mx,sc[m]); }
      float sum=0.f;
      #pragma unroll
      for (int m=0;m<9;++m){ sc[m]=__expf(sc[m]-mx); sum+=sc[m]; }
      float inv = 1.f/sum;
      float o0=0.f;
      #pragma unroll
      for (int m=0;m<9;++m){
        int dr = m/3 - 1, dc = m - (m/3)*3 - 1;
        int nr_ = (b<<12) + ((br+dr)<<6) + (bc+dc);
        o0 += sc[m]*inv * qkvR[(size_t)(68+slot)*NROWS + nr_];
      }
      sO[lr2][slot] = o0;
    }
    __syncthreads();
    // ---- h' = hnew(prestaged) + o @ M^T + b2 : slot -> j = slot<32 ----
    if (slot < 32) {
      float a = sB2[slot];
      #pragma unroll
      for (int e=0;e<34;++e) a += sO[lr2][e] * sM[slot][e];
      sHp[lr2][slot] += a;
    }
    __syncthreads();
    // ---- g = h' @ Wfc2^T + b ----
    if (slot < 32) {
      float g = sBfc2[slot];
      #pragma unroll
      for (int i=0;i<32;++i) g += sHp[lr2][i] * sWfc2[slot][i];
      sG[lr2][slot] = g;
    }
    __syncthreads();
    // ---- layernorm -> sPred ----
    if (slot < 32) {
      float mu=0.f;
      #pragma unroll
      for (int i=0;i<32;++i) mu += sG[lr2][i];
      mu *= 0.03125f;
      float var=0.f;
      #pragma unroll
      for (int i=0;i<32;++i){ float d=sG[lr2][i]-mu; var += d*d; }
      var *= 0.03125f;
      float rs = rsqrtf(var + 1e-5f);
      sPred[lr2][slot] = (sG[lr2][slot]-mu)*rs*sLng[slot] + sLnb[slot];
    }
    __syncthreads();
    // ---- coalesced out write (block chunk = 512 contiguous floats) ----
    if (tid < 512) {
      size_t obase = ((size_t)stepB*NROWS + base)*32;
      out[obase + tid] = sPred[tid>>5][tid&31];
    }
  }

  if (stepA >= 0) {
    // ---- h_new = tanh(inp@W1^T + h'@W2^T + b) : slot -> j = slot<32 ----
    if (slot < 32) {
      float a = sB12[slot];
      if (stepA < 10) {
        #pragma unroll
        for (int i=0;i<32;++i)
          a += sX[lr2][i]*sW1[slot][i] + sHp[lr2][i]*sW2[slot][i];
      } else {
        #pragma unroll
        for (int i=0;i<32;++i)
          a += sPred[lr2][i]*sW1[slot][i] + sHp[lr2][i]*sW2[slot][i];
      }
      float t0 = tanhf(a);
      sHn[lr2][slot] = t0;
      hnewG[(size_t)slot*NROWS + r2] = t0;          // 64B segments per slot
    }
    __syncthreads();
    // ---- qkv = [h_new, pl] @ W_in^T + b_in : slot -> e = slot, slot+64 ----
    float hn[32];
    #pragma unroll
    for (int f=0;f<32;++f) hn[f]=sHn[lr2][f];
    const float pl0 = gr*0.015625f, pl1 = c*0.015625f;
    #pragma unroll
    for (int k=0;k<2;++k){
      int e = slot + 64*k;
      if (e < 102) {
        float acc = sBin[e];
        #pragma unroll
        for (int f=0;f<32;++f) acc += hn[f]*sWin[e][f];
        acc += pl0*sWin[e][32] + pl1*sWin[e][33];
        qkvW[(size_t)e*NROWS + r2] = acc;           // 64B segments per e
      }
    }
  }
}

extern "C" void kernel_launch(void* const* d_in, const int* in_sizes, int n_in,
                              void* d_out, int out_size, void* d_ws, size_t ws_size,
                              hipStream_t stream) {
  const float* x     = (const float*)d_in[0];
  const float* W_x2h = (const float*)d_in[1];
  const float* b_x2h = (const float*)d_in[2];
  const float* W_h2h = (const float*)d_in[3];
  const float* b_h2h = (const float*)d_in[4];
  const float* W_fc2 = (const float*)d_in[5];
  const float* b_fc2 = (const float*)d_in[6];
  const float* ln_g  = (const float*)d_in[7];
  const float* ln_b  = (const float*)d_in[8];
  const float* W_fcsa= (const float*)d_in[9];
  const float* b_fcsa= (const float*)d_in[10];
  const float* W_in  = (const float*)d_in[11];
  const float* b_in  = (const float*)d_in[12];
  const float* W_out = (const float*)d_in[13];
  const float* b_out = (const float*)d_in[14];
  float* ws = (float*)d_ws;
  float* out = (float*)d_out;

  setup_kernel<<<8, 256, 0, stream>>>(W_x2h,b_x2h,W_h2h,b_h2h,W_fc2,b_fc2,ln_g,ln_b,
                                      W_fcsa,b_fcsa,W_in,b_in,W_out,b_out, ws);
  for (int i=0;i<60;++i){
    int stepB = i-1;
    int stepA = (i<=58)? i : -1;
    const float* qR = ws + OFF_QKV0 + (size_t)((i+1)&1)*QKVN;  // qkv of step i-1
    float*       qW = ws + OFF_QKV0 + (size_t)(i&1)*QKVN;      // qkv of step i
    step_kernel<<<NBLK, TPB, 0, stream>>>(ws, qR, qW, ws+OFF_HNEW, x, out, stepB, stepA);
  }
}